// Round 13
// baseline (296.385 us; speedup 1.0000x reference)
//
#include <hip/hip_runtime.h>
#include <math.h>

// Problem constants (from reference)
#define NDIM 64
#define NK   128
#define ALPHA_DP 1.0
#define TAU0 0.0
#define C0v  1.0
#define N0v  ((double)(NDIM + 2))
#define B0v  1.0

#define ITERS 4          // 64-point iterations per block (grid = N/256 = 1024)
#define NSLOT 64         // ll partial-sum slots

typedef __attribute__((ext_vector_type(8))) short bf16x8;
typedef __attribute__((ext_vector_type(4))) float f32x4;
typedef __attribute__((ext_vector_type(2))) float f32x2;

// ---------------- device math helpers ----------------
__device__ double digamma_d(double x) {
    double r = 0.0;
    while (x < 6.0) { r -= 1.0 / x; x += 1.0; }
    double inv = 1.0 / x, inv2 = inv * inv;
    double s = log(x) - 0.5 * inv
        - inv2 * (1.0/12.0 - inv2 * (1.0/120.0 - inv2 * (1.0/252.0
            - inv2 * (1.0/240.0 - inv2 * (1.0/132.0)))));
    return s + r;
}

__device__ inline unsigned pack_bf16_hi(float a, float b) {
    // dword = {bf16(a) lo16, bf16(b) hi16}; truncation split
    return (__float_as_uint(a) >> 16) | (__float_as_uint(b) & 0xffff0000u);
}

// DPP cross-lane mov (VALU pipe). CTRL compile-time (builtin requirement).
// 0xB1=quad xor1, 0x4E=quad xor2, 0x124=row_ror:4, 0x128=row_ror:8.
// xor1+xor2+ror4+ror8 = full 16-lane-row reduce (all lanes get the total).
template <int CTRL>
__device__ inline float dpp_mov(float v) {
    return __uint_as_float((unsigned)__builtin_amdgcn_update_dpp(
        0, (int)__float_as_uint(v), CTRL, 0xF, 0xF, true));
}

// fragment-major ushort index for W tables, 16x16x32 MFMA B-operand layout
// (r12-verified: absmax passed). feature f (0..127), cluster k.
// layout: [s=f>>5][t=k>>4][hi=(f>>3)&3][n=k&15][j=f&7]
__device__ inline int widx(int f, int k) {
    int s = f >> 5, hi = (f >> 3) & 3, j = f & 7, t = k >> 4, n = k & 15;
    return (((s * 8 + t) * 4 + hi) * 16 + n) * 8 + j;
}

// ---------------- kernel 1: cluster prep (1 block, 1024 threads) ----------------
__global__ __launch_bounds__(1024) void prep_kernel(
    const float* __restrict__ nat_u,
    const float* __restrict__ nat_v,
    const float* __restrict__ nat_tau,
    const float* __restrict__ nat_c,
    const float* __restrict__ nat_n,
    const float* __restrict__ nat_B,
    double* __restrict__ scal,
    double* __restrict__ slots,
    float* __restrict__ constk,
    unsigned short* __restrict__ Wh,
    unsigned short* __restrict__ Wl) {
    const int t = threadIdx.x;
    const int k = t >> 3;            // cluster 0..127
    const int j = t & 7;             // sub-lane within cluster
    const int D = NDIM;

    double u = (double)nat_u[k] + 1.0;
    double v = (double)nat_v[k] + 1.0;
    double c = (double)nat_c[k];
    double n = (double)nat_n[k] - (double)D - 2.0;
    double a1 = 0.5 * n;
    const double a0g = 0.5 * N0v;    // 33.0
    const double b0g = 0.5 * B0v;    // 0.5
    const double log_b0g = log(b0g);

    double s_logB = 0.0, s_t2nb = 0.0, s_nb = 0.0, s_klg = 0.0, s_kln = 0.0;

#pragma unroll
    for (int i = 0; i < 8; ++i) {
        int d = j * 8 + i;
        double tau = (double)nat_tau[k * D + d] / c;
        double B   = (double)nat_B[k * D + d] - c * tau * tau;
        double nb  = n / B;
        float wx = (float)(tau * nb);          // coefficient on x_d   (feature d)
        float wy = (float)(-0.5 * nb);         // coefficient on y_d=x_d^2-1 (feature 64+d)
        unsigned bx = __float_as_uint(wx), by = __float_as_uint(wy);
        float hx = __uint_as_float(bx & 0xffff0000u);
        float hy = __uint_as_float(by & 0xffff0000u);
        Wh[widx(d, k)]      = (unsigned short)(bx >> 16);
        Wh[widx(64 + d, k)] = (unsigned short)(by >> 16);
        Wl[widx(d, k)]      = (unsigned short)(__float_as_uint(wx - hx) >> 16);
        Wl[widx(64 + d, k)] = (unsigned short)(__float_as_uint(wy - hy) >> 16);

        double b1 = 0.5 * B;
        double lb1 = log(b1);
        s_logB += lb1;
        s_t2nb += tau * tau * nb;
        s_nb   += nb;
        s_klg  += a0g * (lb1 - log_b0g) + a1 * (b0g - b1) / b1;
        s_kln  += C0v * nb * (tau - TAU0) * (tau - TAU0);
    }

    // reduce across the 8 sub-lanes of this cluster (consecutive lanes in wave)
#pragma unroll
    for (int m = 1; m < 8; m <<= 1) {
        s_logB += __shfl_xor(s_logB, m, 64);
        s_t2nb += __shfl_xor(s_t2nb, m, 64);
        s_nb   += __shfl_xor(s_nb,   m, 64);
        s_klg  += __shfl_xor(s_klg,  m, 64);
        s_kln  += __shfl_xor(s_kln,  m, 64);
    }

    // lane-specialized transcendentals: 1 digamma + 1 lgamma per lane
    double arg1 = (j == 0) ? u : (j == 1) ? v : (j == 2) ? (u + v) : a1;
    double dg = digamma_d(arg1);
    double arg2 = (j == 4) ? u : (j == 5) ? v : (j == 6) ? (u + v)
                : (j == 7) ? a1 : a0g;
    double lg = lgamma(arg2);

    const int base = (t & 63) & ~7;  // base lane of this cluster's 8-lane group
    double dg_u   = __shfl(dg, base + 0, 64);
    double dg_v   = __shfl(dg, base + 1, 64);
    double dg_uv  = __shfl(dg, base + 2, 64);
    double dg_a1  = __shfl(dg, base + 3, 64);
    double lg_a0g = __shfl(lg, base + 0, 64);
    double lg_u   = __shfl(lg, base + 4, 64);
    double lg_v   = __shfl(lg, base + 5, 64);
    double lg_uv  = __shfl(lg, base + 6, 64);
    double lg_a1  = __shfl(lg, base + 7, 64);

    __shared__ double sh_stick[NK], sh_cp[NK], sh_kl[NK];
    if (j == 0) {
        const double LOG2PI = 1.8378770664093454836;
        double e_log_det = (double)D * dg_a1 - s_logB;
        // ck without the cross-cluster stick prefix (added below)
        double cp = dg_u - dg_uv + 0.5 * (e_log_det - (double)D * LOG2PI
                    - s_t2nb - (double)D / c - s_nb);
        // KL(Beta(u,v)||Beta(1,1)): constant term lgamma(2)-2*lgamma(1) = 0
        double kl_beta = lg_uv - lg_u - lg_v
            + (u - 1.0) * dg_u + (v - 1.0) * dg_v + (2.0 - u - v) * dg_uv;
        double kl_gamma = (double)D * ((a1 - a0g) * dg_a1 - lg_a1 + lg_a0g) + s_klg;
        double kl_norm = 0.5 * ((double)D * (log(c / C0v) + C0v / c - 1.0) + s_kln);
        sh_stick[k] = dg_v - dg_uv;
        sh_cp[k]    = cp;
        sh_kl[k]    = kl_beta + kl_gamma + kl_norm;
    }
    if (t < NSLOT) slots[t] = 0.0;   // zero ll partials (ws is poisoned)
    __syncthreads();

    if (t < NK) {
        double pre = 0.0;
        for (int q = 0; q < t; ++q) pre += sh_stick[q];   // exclusive prefix
        constk[t] = (float)(sh_cp[t] + pre);
    }
    if (t == 0) {
        double tot = 0.0;
        for (int q = 0; q < NK; ++q) tot += sh_kl[q];
        scal[1] = tot;
        scal[0] = 0.0;
    }
}

// ---------------- kernel 2: barrier-free MFMA maha + in-wave softmax ----------------
// 16x16x32 structure, occupancy-corrected vs r12 (which stayed at 8 waves/CU):
// (a) 256-thread blocks = 1 wave/SIMD granularity (r12's 512-block quantized
//     the 160-reg/wave budget down to 2 waves/SIMD; 512/160 = 3 fit).
// (b) Wh-only in LDS (32KB) + 8KB staging = 40KB/block -> 3 blocks x 40KB =
//     120KB <= 160KB; Wl from global (32KB L2-resident, 1KB/instr coalesced).
// -> 3 blocks/CU = 12 waves/CU (1.5x r10's 8), natural regs (r12 measured
//    128 arch + 32 acc = 160; no forced cap -- r1/6/7/11 spill rule).
// (c) stores back to ONE full 512B row per instruction (r10's RMW fix; r12's
//     2x256B variant re-triggered read-for-ownership, FETCH 206MB).
// Staging swizzle: row hi stored with +8*hi rotation -> write conflicts 2-way
// (free), reads 2-way (free).
__global__ __launch_bounds__(256, 2) void maha_kernel(
    const float* __restrict__ x,
    const float* __restrict__ constk,
    const uint4* __restrict__ WhG,                 // 32 KB fragment-major
    const unsigned short* __restrict__ WlG,        // 32 KB fragment-major
    float* __restrict__ r,
    double* __restrict__ slots) {
    __shared__ __align__(16) uint4 W[2048];        // 32 KB (Wh only)
    __shared__ __align__(16) float SB[4][512];     // 8 KB store-transpose staging
    const int tid = threadIdx.x;
#pragma unroll
    for (int i = 0; i < 8; ++i) W[i * 256 + tid] = WhG[i * 256 + tid];
    __syncthreads();                               // only barrier in the kernel
    const unsigned short* Wh = (const unsigned short*)W;

    const int lane = tid & 63;
    const int w    = tid >> 6;        // wave 0..3
    const int hi   = lane >> 4;       // k-group / row-group 0..3
    const int n    = lane & 15;       // point row within group / col within cluster-tile
    const int l2   = (lane << 1) & 127;   // 2*lane mod 128 (readback col pair)
    float* sb = SB[w];

    float ck[8];
#pragma unroll
    for (int t = 0; t < 8; ++t) ck[t] = constk[t * 16 + n];

    double dsum = 0.0;

#pragma unroll 1
    for (int it = 0; it < ITERS; ++it) {
        const long n0 = (long)blockIdx.x * (64 * ITERS) + it * 64 + w * 16;

        // A-frag x data: lane(hi,n) needs dims hi*8..+8 and 32+hi*8..+8 of row n0+n.
        const float* xr = x + (n0 + n) * NDIM + hi * 8;
        f32x4 xa0 = *(const f32x4*)(xr);
        f32x4 xa1 = *(const f32x4*)(xr + 4);
        f32x4 xb0 = *(const f32x4*)(xr + 32);
        f32x4 xb1 = *(const f32x4*)(xr + 36);

        f32x4 acc[8];                 // 8 cluster-tiles x 4 rows
#pragma unroll
        for (int t = 0; t < 8; ++t) {
            acc[t][0] = 0.f; acc[t][1] = 0.f; acc[t][2] = 0.f; acc[t][3] = 0.f;
        }

        // ---- K loop: 4 ksteps (s=0: x lo-dims, 1: x hi-dims, 2: y lo, 3: y hi) ----
#pragma unroll
        for (int s = 0; s < 4; ++s) {
            float fe[8], lo[8];
#pragma unroll
            for (int e = 0; e < 8; ++e) {
                float xv = (s & 1) ? ((e < 4) ? xb0[e] : xb1[e - 4])
                                   : ((e < 4) ? xa0[e] : xa1[e - 4]);
                fe[e] = (s < 2) ? xv : fmaf(xv, xv, -1.0f);   // x or y=x^2-1
            }
#pragma unroll
            for (int e = 0; e < 8; ++e) {
                float h = __uint_as_float(__float_as_uint(fe[e]) & 0xffff0000u);
                lo[e] = fe[e] - h;
            }
            union { bf16x8 v; unsigned d[4]; } ah, al;
#pragma unroll
            for (int q = 0; q < 4; ++q) {
                ah.d[q] = pack_bf16_hi(fe[2 * q], fe[2 * q + 1]);
                al.d[q] = pack_bf16_hi(lo[2 * q], lo[2 * q + 1]);
            }
            __builtin_amdgcn_s_setprio(1);
#pragma unroll
            for (int t = 0; t < 8; ++t) {
                const int bo = ((s * 8 + t) * 4 + hi) * 128 + n * 8;
                bf16x8 bh = *(const bf16x8*)(Wh  + bo);
                bf16x8 bl = *(const bf16x8*)(WlG + bo);
                acc[t] = __builtin_amdgcn_mfma_f32_16x16x32_bf16(ah.v, bh, acc[t], 0, 0, 0);
                acc[t] = __builtin_amdgcn_mfma_f32_16x16x32_bf16(al.v, bh, acc[t], 0, 0, 0);
                acc[t] = __builtin_amdgcn_mfma_f32_16x16x32_bf16(ah.v, bl, acc[t], 0, 0, 0);
            }
            __builtin_amdgcn_s_setprio(0);
        }

        // ---- softmax + full-row store, per reg (4 rows at a time, one per group) ----
        // C/D: col = n (cluster t*16+n), row = hi*4 + reg (r12-verified layout).
        // Reduce over 128 clusters = 8 local values + 16-lane all-DPP butterfly.
#pragma unroll
        for (int reg = 0; reg < 4; ++reg) {
            float l[8];
#pragma unroll
            for (int t = 0; t < 8; ++t) l[t] = acc[t][reg] + ck[t];
            float M = fmaxf(fmaxf(fmaxf(l[0], l[1]), fmaxf(l[2], l[3])),
                            fmaxf(fmaxf(l[4], l[5]), fmaxf(l[6], l[7])));
            M = fmaxf(M, dpp_mov<0xB1>(M));    // xor1
            M = fmaxf(M, dpp_mov<0x4E>(M));    // xor2
            M = fmaxf(M, dpp_mov<0x124>(M));   // row_ror:4
            M = fmaxf(M, dpp_mov<0x128>(M));   // row_ror:8
            float e[8];
#pragma unroll
            for (int t = 0; t < 8; ++t) e[t] = __expf(l[t] - M);
            float S = ((e[0] + e[1]) + (e[2] + e[3])) + ((e[4] + e[5]) + (e[6] + e[7]));
            S += dpp_mov<0xB1>(S);
            S += dpp_mov<0x4E>(S);
            S += dpp_mov<0x124>(S);
            S += dpp_mov<0x128>(S);
            const float inv = __builtin_amdgcn_rcpf(S);

            // stage: group hi's row (global row n0+hi*4+reg) at slot hi,
            // logical col c=16t+n stored at phys (c + 8*hi) & 127
            // -> per write instruction each bank hit by exactly 2 groups (free)
#pragma unroll
            for (int t = 0; t < 8; ++t) {
                const int c = 16 * t + n;
                sb[hi * 128 + ((c + 8 * hi) & 127)] = e[t] * inv;
            }
            // read back + store: one FULL 512B row per instruction (no RMW).
            // row ri: lane reads phys (2*lane + 8*ri)&127 = logical 2*lane.
#pragma unroll
            for (int ri = 0; ri < 4; ++ri) {
                f32x2 v = *(const f32x2*)(sb + ri * 128 + ((l2 + 8 * ri) & 127));
                float* rp = r + (n0 + ri * 4 + reg) * (long)NK;
                *(f32x2*)(rp + l2) = v;
            }
            dsum += (double)(M + __logf(S));   // uniform within 16-lane group
        }
    }

    // ---- ll: each group covers distinct rows; combine 4 groups, 1 atomic/wave ----
    double dtot = __shfl(dsum, 0, 64) + __shfl(dsum, 16, 64)
                + __shfl(dsum, 32, 64) + __shfl(dsum, 48, 64);
    if (lane == 0) atomicAdd(&slots[(blockIdx.x * 4 + w) & (NSLOT - 1)], dtot);
}

// ---------------- kernel 3: finalize scalar ----------------
__global__ void finalize_kernel(const double* __restrict__ scal,
                                const double* __restrict__ slots,
                                float* __restrict__ out) {
    double ll = 0.0;
    for (int i = 0; i < NSLOT; ++i) ll += slots[i];
    out[0] = (float)(scal[1] - ll);   // -elbo = kl_total - ll
}

extern "C" void kernel_launch(void* const* d_in, const int* in_sizes, int n_in,
                              void* d_out, int out_size, void* d_ws, size_t ws_size,
                              hipStream_t stream) {
    const float* x       = (const float*)d_in[0];
    const float* nat_u   = (const float*)d_in[1];
    const float* nat_v   = (const float*)d_in[2];
    const float* nat_tau = (const float*)d_in[3];
    const float* nat_c   = (const float*)d_in[4];
    const float* nat_n   = (const float*)d_in[5];
    const float* nat_B   = (const float*)d_in[6];

    const int N = in_sizes[0] / NDIM;
    float* out = (float*)d_out;

    // ws layout: scal 16B | slots 512B | constk 512B | Wh 32KB | Wl 32KB (16B-aligned)
    double* scal       = (double*)d_ws;
    double* slots      = (double*)((char*)d_ws + 16);
    float* constk      = (float*)((char*)d_ws + 16 + 512);
    unsigned short* Wh = (unsigned short*)((char*)d_ws + 1040);
    unsigned short* Wl = (unsigned short*)((char*)d_ws + 1040 + 32768);
    const uint4* WhG   = (const uint4*)((char*)d_ws + 1040);

    prep_kernel<<<1, 1024, 0, stream>>>(nat_u, nat_v, nat_tau, nat_c, nat_n, nat_B,
                                        scal, slots, constk, Wh, Wl);
    maha_kernel<<<N / (64 * ITERS), 256, 0, stream>>>(x, constk, WhG, Wl, out, slots);
    finalize_kernel<<<1, 1, 0, stream>>>(scal, slots, out + (size_t)N * NK);
}

// Round 14
// 223.852 us; speedup vs baseline: 1.3240x; 1.3240x over previous
//
#include <hip/hip_runtime.h>
#include <math.h>

// Problem constants (from reference)
#define NDIM 64
#define NK   128
#define ALPHA_DP 1.0
#define TAU0 0.0
#define C0v  1.0
#define N0v  ((double)(NDIM + 2))
#define B0v  1.0

#define ITERS 4          // 128-point iterations per block (grid = N/512 = 512)
#define NSLOT 64         // ll partial-sum slots

typedef __attribute__((ext_vector_type(8))) short bf16x8;
typedef __attribute__((ext_vector_type(16))) float f32x16;
typedef __attribute__((ext_vector_type(4))) float f32x4;

// ---------------- device math helpers ----------------
__device__ double digamma_d(double x) {
    double r = 0.0;
    while (x < 6.0) { r -= 1.0 / x; x += 1.0; }
    double inv = 1.0 / x, inv2 = inv * inv;
    double s = log(x) - 0.5 * inv
        - inv2 * (1.0/12.0 - inv2 * (1.0/120.0 - inv2 * (1.0/252.0
            - inv2 * (1.0/240.0 - inv2 * (1.0/132.0)))));
    return s + r;
}

__device__ inline unsigned pack_bf16_hi(float a, float b) {
    // dword = {bf16(a) lo16, bf16(b) hi16}; truncation split
    return (__float_as_uint(a) >> 16) | (__float_as_uint(b) & 0xffff0000u);
}

// DPP cross-lane mov (VALU pipe). CTRL compile-time (builtin requirement).
// 0xB1=quad xor1, 0x4E=quad xor2, 0x124=row_ror:4, 0x128=row_ror:8.
template <int CTRL>
__device__ inline float dpp_mov(float v) {
    return __uint_as_float((unsigned)__builtin_amdgcn_update_dpp(
        0, (int)__float_as_uint(v), CTRL, 0xF, 0xF, true));
}

// Cross-16 (lane ^ 16) combine. gfx950 has v_permlane16_swap_b32 (VALU):
// permlane16_swap(x,x) -> p[0]={r0,r0,r2,r2}, p[1]={r1,r1,r3,r3} per 32-half,
// so own+partner == p[0] op p[1] for EVERY lane. Falls back to DS shuffle.
#if __has_builtin(__builtin_amdgcn_permlane16_swap)
__device__ inline float red16_max(float v) {
    auto p = __builtin_amdgcn_permlane16_swap(__float_as_uint(v),
                                              __float_as_uint(v), false, false);
    return fmaxf(__uint_as_float(p[0]), __uint_as_float(p[1]));
}
__device__ inline float red16_sum(float v) {
    auto p = __builtin_amdgcn_permlane16_swap(__float_as_uint(v),
                                              __float_as_uint(v), false, false);
    return __uint_as_float(p[0]) + __uint_as_float(p[1]);
}
#else
__device__ inline float red16_max(float v) { return fmaxf(v, __shfl_xor(v, 16, 64)); }
__device__ inline float red16_sum(float v) { return v + __shfl_xor(v, 16, 64); }
#endif

// fragment-major ushort index for W tables (32x32x16 B-operand layout):
// feature f (0..127: x dims then y dims), cluster k.
// layout: [s=k>>5][kc=f>>4][g=(f>>3)&1][n=k&31][j=f&7]
__device__ inline int widx(int f, int k) {
    int kc = f >> 4, g = (f >> 3) & 1, j = f & 7, s = k >> 5, n = k & 31;
    return ((s * 8 + kc) * 2 + g) * 256 + n * 8 + j;
}

// ---------------- kernel 1: cluster prep (1 block, 1024 threads) ----------------
__global__ __launch_bounds__(1024) void prep_kernel(
    const float* __restrict__ nat_u,
    const float* __restrict__ nat_v,
    const float* __restrict__ nat_tau,
    const float* __restrict__ nat_c,
    const float* __restrict__ nat_n,
    const float* __restrict__ nat_B,
    double* __restrict__ scal,
    double* __restrict__ slots,
    float* __restrict__ constk,
    unsigned short* __restrict__ Wh,
    unsigned short* __restrict__ Wl) {
    const int t = threadIdx.x;
    const int k = t >> 3;            // cluster 0..127
    const int j = t & 7;             // sub-lane within cluster
    const int D = NDIM;

    double u = (double)nat_u[k] + 1.0;
    double v = (double)nat_v[k] + 1.0;
    double c = (double)nat_c[k];
    double n = (double)nat_n[k] - (double)D - 2.0;
    double a1 = 0.5 * n;
    const double a0g = 0.5 * N0v;    // 33.0
    const double b0g = 0.5 * B0v;    // 0.5
    const double log_b0g = log(b0g);

    double s_logB = 0.0, s_t2nb = 0.0, s_nb = 0.0, s_klg = 0.0, s_kln = 0.0;

#pragma unroll
    for (int i = 0; i < 8; ++i) {
        int d = j * 8 + i;
        double tau = (double)nat_tau[k * D + d] / c;
        double B   = (double)nat_B[k * D + d] - c * tau * tau;
        double nb  = n / B;
        float wx = (float)(tau * nb);          // coefficient on x_d   (feature d)
        float wy = (float)(-0.5 * nb);         // coefficient on y_d=x_d^2-1 (feature 64+d)
        unsigned bx = __float_as_uint(wx), by = __float_as_uint(wy);
        float hx = __uint_as_float(bx & 0xffff0000u);
        float hy = __uint_as_float(by & 0xffff0000u);
        Wh[widx(d, k)]      = (unsigned short)(bx >> 16);
        Wh[widx(64 + d, k)] = (unsigned short)(by >> 16);
        Wl[widx(d, k)]      = (unsigned short)(__float_as_uint(wx - hx) >> 16);
        Wl[widx(64 + d, k)] = (unsigned short)(__float_as_uint(wy - hy) >> 16);

        double b1 = 0.5 * B;
        double lb1 = log(b1);
        s_logB += lb1;
        s_t2nb += tau * tau * nb;
        s_nb   += nb;
        s_klg  += a0g * (lb1 - log_b0g) + a1 * (b0g - b1) / b1;
        s_kln  += C0v * nb * (tau - TAU0) * (tau - TAU0);
    }

    // reduce across the 8 sub-lanes of this cluster (consecutive lanes in wave)
#pragma unroll
    for (int m = 1; m < 8; m <<= 1) {
        s_logB += __shfl_xor(s_logB, m, 64);
        s_t2nb += __shfl_xor(s_t2nb, m, 64);
        s_nb   += __shfl_xor(s_nb,   m, 64);
        s_klg  += __shfl_xor(s_klg,  m, 64);
        s_kln  += __shfl_xor(s_kln,  m, 64);
    }

    // lane-specialized transcendentals: 1 digamma + 1 lgamma per lane
    double arg1 = (j == 0) ? u : (j == 1) ? v : (j == 2) ? (u + v) : a1;
    double dg = digamma_d(arg1);
    double arg2 = (j == 4) ? u : (j == 5) ? v : (j == 6) ? (u + v)
                : (j == 7) ? a1 : a0g;
    double lg = lgamma(arg2);

    const int base = (t & 63) & ~7;  // base lane of this cluster's 8-lane group
    double dg_u   = __shfl(dg, base + 0, 64);
    double dg_v   = __shfl(dg, base + 1, 64);
    double dg_uv  = __shfl(dg, base + 2, 64);
    double dg_a1  = __shfl(dg, base + 3, 64);
    double lg_a0g = __shfl(lg, base + 0, 64);
    double lg_u   = __shfl(lg, base + 4, 64);
    double lg_v   = __shfl(lg, base + 5, 64);
    double lg_uv  = __shfl(lg, base + 6, 64);
    double lg_a1  = __shfl(lg, base + 7, 64);

    __shared__ double sh_stick[NK], sh_cp[NK], sh_kl[NK];
    if (j == 0) {
        const double LOG2PI = 1.8378770664093454836;
        double e_log_det = (double)D * dg_a1 - s_logB;
        // ck without the cross-cluster stick prefix (added below)
        double cp = dg_u - dg_uv + 0.5 * (e_log_det - (double)D * LOG2PI
                    - s_t2nb - (double)D / c - s_nb);
        // KL(Beta(u,v)||Beta(1,1)): constant term lgamma(2)-2*lgamma(1) = 0
        double kl_beta = lg_uv - lg_u - lg_v
            + (u - 1.0) * dg_u + (v - 1.0) * dg_v + (2.0 - u - v) * dg_uv;
        double kl_gamma = (double)D * ((a1 - a0g) * dg_a1 - lg_a1 + lg_a0g) + s_klg;
        double kl_norm = 0.5 * ((double)D * (log(c / C0v) + C0v / c - 1.0) + s_kln);
        sh_stick[k] = dg_v - dg_uv;
        sh_cp[k]    = cp;
        sh_kl[k]    = kl_beta + kl_gamma + kl_norm;
    }
    if (t < NSLOT) slots[t] = 0.0;   // zero ll partials (ws is poisoned)
    __syncthreads();

    if (t < NK) {
        double pre = 0.0;
        for (int q = 0; q < t; ++q) pre += sh_stick[q];   // exclusive prefix
        constk[t] = (float)(sh_cp[t] + pre);
    }
    if (t == 0) {
        double tot = 0.0;
        for (int q = 0; q < NK; ++q) tot += sh_kl[q];
        scal[1] = tot;
        scal[0] = 0.0;
    }
}

// ---------------- kernel 2: barrier-free MFMA maha + in-wave softmax ----------------
// r10 base (best measured: 223.9us total; 32x32 MFMA, W in LDS 64KB, ITERS=4,
// grid 512, x prefetch, setprio, DPP softmax, staged full-row stores, (256,2)
// natural 128+64 regs no spill). 16x16 branch falsified (r12/r13: occupancy
// quantizes at vgpr<=128 -> can't reach 3 waves/SIMD; 2x B-fragment DS/point).
// THIS ROUND, on r10:
// (a) paired-rg staging: rows (p,p+1) staged together, read b128, store ONE
//     1KB dwordx4 per 2 rows -> DS reads 32->16/iter, stores 32->16/iter.
// (b) cross-16 reduce via v_permlane16_swap (VALU) replacing __shfl_xor DS op
//     (guarded; fallback = r10 exactly). Removes 32 DS ops + ~120cy DS latency
//     from each rg's softmax critical path.
__global__ __launch_bounds__(256, 2) void maha_kernel(
    const float* __restrict__ x,
    const float* __restrict__ constk,
    const uint4* __restrict__ Wg,      // WhL then WlL, 64 KB fragment-major
    float* __restrict__ r,
    double* __restrict__ slots) {
    __shared__ __align__(16) uint4 W[4096];          // 64 KB
    __shared__ __align__(16) float SB[4][512];       // 8 KB store-transpose staging
    const int tid = threadIdx.x;
#pragma unroll
    for (int i = 0; i < 16; ++i) W[i * 256 + tid] = Wg[i * 256 + tid];
    __syncthreads();                                  // only barrier in the kernel
    const unsigned short* Wh = (const unsigned short*)W;           // [0,32768)
    const unsigned short* Wl = (const unsigned short*)(W + 2048);  // [32768,65536)

    const int lane = tid & 63;
    const int w    = tid >> 6;
    const int g    = lane >> 5;
    const int m0   = lane & 31;
    float* sbw = SB[w];               // 512 floats: rows {pa,pa+1}(g0), {pa+4,pa+5}(g1)

    float ck[4];
#pragma unroll
    for (int s = 0; s < 4; ++s) ck[s] = constk[s * 32 + m0];

    double dsum = 0.0;

    // this lane's x base: row (blockbase + w*32 + m0), dims {g*8+16t .. +8}
    const long xrow0 = (long)blockIdx.x * (128 * ITERS) + w * 32 + m0;
    const float* xp = x + xrow0 * NDIM + g * 8;

    // ---- prefetch it=0 (8 x 16B) ----
    f32x4 cur[8], nxt[8];
#pragma unroll
    for (int t = 0; t < 4; ++t) {
        cur[2 * t]     = *(const f32x4*)(xp + t * 16);
        cur[2 * t + 1] = *(const f32x4*)(xp + t * 16 + 4);
    }

#pragma unroll 1
    for (int it = 0; it < ITERS; ++it) {
        // ---- issue next iteration's x loads early (latency hidden under K-loop) ----
        if (it + 1 < ITERS) {
            const float* xn = xp + (long)(it + 1) * (128 * NDIM);
#pragma unroll
            for (int t = 0; t < 4; ++t) {
                nxt[2 * t]     = *(const f32x4*)(xn + t * 16);
                nxt[2 * t + 1] = *(const f32x4*)(xn + t * 16 + 4);
            }
        }

        const long n0 = (long)blockIdx.x * (128 * ITERS) + it * 128 + w * 32;

        f32x16 acc[4];
#pragma unroll
        for (int s = 0; s < 4; ++s)
#pragma unroll
            for (int i = 0; i < 16; ++i) acc[s][i] = 0.f;

        // ---- K loop: 8 chunks x 4 strips x (hh, lh, hl) ----
#pragma unroll
        for (int c = 0; c < 8; ++c) {
            float fe[8], lo[8];
#pragma unroll
            for (int e = 0; e < 8; ++e) {
                float xv = cur[(c & 3) * 2 + (e >> 2)][e & 3];
                fe[e] = (c < 4) ? xv : fmaf(xv, xv, -1.0f);   // x or y=x^2-1
            }
#pragma unroll
            for (int e = 0; e < 8; ++e) {
                float h = __uint_as_float(__float_as_uint(fe[e]) & 0xffff0000u);
                lo[e] = fe[e] - h;
            }
            union { bf16x8 v; unsigned d[4]; } ah, al;
#pragma unroll
            for (int q = 0; q < 4; ++q) {
                ah.d[q] = pack_bf16_hi(fe[2 * q], fe[2 * q + 1]);
                al.d[q] = pack_bf16_hi(lo[2 * q], lo[2 * q + 1]);
            }
            const int bidx = (c * 2 + g) * 256 + m0 * 8;      // ushort index
            __builtin_amdgcn_s_setprio(1);
#pragma unroll
            for (int s = 0; s < 4; ++s) {
                bf16x8 bh = *(const bf16x8*)(Wh + bidx + s * 4096);
                bf16x8 bl = *(const bf16x8*)(Wl + bidx + s * 4096);
                acc[s] = __builtin_amdgcn_mfma_f32_32x32x16_bf16(ah.v, bh, acc[s], 0, 0, 0);
                acc[s] = __builtin_amdgcn_mfma_f32_32x32x16_bf16(al.v, bh, acc[s], 0, 0, 0);
                acc[s] = __builtin_amdgcn_mfma_f32_32x32x16_bf16(ah.v, bl, acc[s], 0, 0, 0);
            }
            __builtin_amdgcn_s_setprio(0);
        }

        // ---- softmax + staged store, PAIRED rgs (ra even, rb=ra+1) ----
        // C/D: col=lane&31, row p(rg)=(rg&3)+8*(rg>>2)+4*g; p(rb)=p(ra)+1.
        // Reduce domain = 32 lanes of this half: DPP(xor1,xor2,ror4,ror8) + cross-16.
#pragma unroll
        for (int pr = 0; pr < 8; ++pr) {
            const int ra = 2 * pr, rb = 2 * pr + 1;
            float a0 = acc[0][ra] + ck[0], a1 = acc[1][ra] + ck[1];
            float a2 = acc[2][ra] + ck[2], a3 = acc[3][ra] + ck[3];
            float b0 = acc[0][rb] + ck[0], b1 = acc[1][rb] + ck[1];
            float b2 = acc[2][rb] + ck[2], b3 = acc[3][rb] + ck[3];
            float Ma = fmaxf(fmaxf(a0, a1), fmaxf(a2, a3));
            float Mb = fmaxf(fmaxf(b0, b1), fmaxf(b2, b3));
            Ma = fmaxf(Ma, dpp_mov<0xB1>(Ma));   Mb = fmaxf(Mb, dpp_mov<0xB1>(Mb));
            Ma = fmaxf(Ma, dpp_mov<0x4E>(Ma));   Mb = fmaxf(Mb, dpp_mov<0x4E>(Mb));
            Ma = fmaxf(Ma, dpp_mov<0x124>(Ma));  Mb = fmaxf(Mb, dpp_mov<0x124>(Mb));
            Ma = fmaxf(Ma, dpp_mov<0x128>(Ma));  Mb = fmaxf(Mb, dpp_mov<0x128>(Mb));
            Ma = red16_max(Ma);                  Mb = red16_max(Mb);
            float ea0 = __expf(a0 - Ma), ea1 = __expf(a1 - Ma);
            float ea2 = __expf(a2 - Ma), ea3 = __expf(a3 - Ma);
            float eb0 = __expf(b0 - Mb), eb1 = __expf(b1 - Mb);
            float eb2 = __expf(b2 - Mb), eb3 = __expf(b3 - Mb);
            float Sa = (ea0 + ea1) + (ea2 + ea3);
            float Sb = (eb0 + eb1) + (eb2 + eb3);
            Sa += dpp_mov<0xB1>(Sa);    Sb += dpp_mov<0xB1>(Sb);
            Sa += dpp_mov<0x4E>(Sa);    Sb += dpp_mov<0x4E>(Sb);
            Sa += dpp_mov<0x124>(Sa);   Sb += dpp_mov<0x124>(Sb);
            Sa += dpp_mov<0x128>(Sa);   Sb += dpp_mov<0x128>(Sb);
            Sa = red16_sum(Sa);         Sb = red16_sum(Sb);
            const float iva = __builtin_amdgcn_rcpf(Sa);
            const float ivb = __builtin_amdgcn_rcpf(Sb);

            // stage: half g's buffer at [g*256, g*256+256): row p(ra) then p(rb)
            float* sb = sbw + (g << 8);
            sb[m0]            = ea0 * iva;
            sb[m0 + 32]       = ea1 * iva;
            sb[m0 + 64]       = ea2 * iva;
            sb[m0 + 96]       = ea3 * iva;
            sb[128 + m0]      = eb0 * ivb;
            sb[128 + m0 + 32] = eb1 * ivb;
            sb[128 + m0 + 64] = eb2 * ivb;
            sb[128 + m0 + 96] = eb3 * ivb;
            // read back b128 (linear, conflict-free) + 1KB store per 2 rows
            f32x4 v0 = *(const f32x4*)(sbw + lane * 4);          // rows pa, pa+1
            f32x4 v1 = *(const f32x4*)(sbw + 256 + lane * 4);    // rows pa+4, pa+5
            const int pa = (ra & 3) + 8 * (ra >> 2);
            float* rp = r + (n0 + pa) * (long)NK + lane * 4;
            *(f32x4*)(rp)                = v0;
            *(f32x4*)(rp + 4 * NK)       = v1;
            dsum += (double)(Ma + __logf(Sa)) + (double)(Mb + __logf(Sb));
        }

        // rotate prefetched x into place (compiler renames; waitcnt lands here)
        if (it + 1 < ITERS) {
#pragma unroll
            for (int q = 0; q < 8; ++q) cur[q] = nxt[q];
        }
    }

    // ---- ll: combine halves (each half's dsum covers its 16 rows/iter), 1 atomic/wave ----
    double d0  = __shfl(dsum, 0, 64);
    double d32 = __shfl(dsum, 32, 64);
    if (lane == 0) atomicAdd(&slots[(blockIdx.x * 4 + w) & (NSLOT - 1)], d0 + d32);
}

// ---------------- kernel 3: finalize scalar ----------------
__global__ void finalize_kernel(const double* __restrict__ scal,
                                const double* __restrict__ slots,
                                float* __restrict__ out) {
    double ll = 0.0;
    for (int i = 0; i < NSLOT; ++i) ll += slots[i];
    out[0] = (float)(scal[1] - ll);   // -elbo = kl_total - ll
}

extern "C" void kernel_launch(void* const* d_in, const int* in_sizes, int n_in,
                              void* d_out, int out_size, void* d_ws, size_t ws_size,
                              hipStream_t stream) {
    const float* x       = (const float*)d_in[0];
    const float* nat_u   = (const float*)d_in[1];
    const float* nat_v   = (const float*)d_in[2];
    const float* nat_tau = (const float*)d_in[3];
    const float* nat_c   = (const float*)d_in[4];
    const float* nat_n   = (const float*)d_in[5];
    const float* nat_B   = (const float*)d_in[6];

    const int N = in_sizes[0] / NDIM;
    float* out = (float*)d_out;

    // ws layout: scal 16B | slots 512B | constk 512B | Wh 32KB | Wl 32KB (16B-aligned)
    double* scal       = (double*)d_ws;
    double* slots      = (double*)((char*)d_ws + 16);
    float* constk      = (float*)((char*)d_ws + 16 + 512);
    unsigned short* Wh = (unsigned short*)((char*)d_ws + 1040);
    unsigned short* Wl = (unsigned short*)((char*)d_ws + 1040 + 32768);
    const uint4* Wg    = (const uint4*)((char*)d_ws + 1040);

    prep_kernel<<<1, 1024, 0, stream>>>(nat_u, nat_v, nat_tau, nat_c, nat_n, nat_B,
                                        scal, slots, constk, Wh, Wl);
    maha_kernel<<<N / (128 * ITERS), 256, 0, stream>>>(x, constk, Wg, out, slots);
    finalize_kernel<<<1, 1, 0, stream>>>(scal, slots, out + (size_t)N * NK);
}